// Round 7
// baseline (1997.223 us; speedup 1.0000x reference)
//
#include <hip/hip_runtime.h>
#include <hip/hip_bf16.h>
#include <math.h>

// B=512, H=W=64, E=16, K=2, CAP=128, TC=256, NC=1000
// Outputs: final_logits[512,1000], routing_scores[512,16], D[512,16] (fp32)
//
// conv2/3/4: implicit-GEMM MFMA, fp16 two-term split (3 MFMAs / fp32 product).
// R6 passed @1924us: conv4 MfmaUtil 42%, occupancy 20.5% (1 wave/SIMD/block).
// R7 change: 16-row tile, 512 threads (8 waves/block), LDS 78.4KB -> exactly
// 2 blocks/CU resident = 4 waves/SIMD; halved barriers; setprio around MFMA.

typedef _Float16 f16;
typedef f16 half8 __attribute__((ext_vector_type(8)));
typedef float f32x4v __attribute__((ext_vector_type(4)));

// ---------------------------------------------------------------------------
// conv1: 3->32, 64x64, vector fp32, epilogue writes NHWC f16 hi/lo planes.
// ---------------------------------------------------------------------------
__global__ __launch_bounds__(256) void conv1_kernel(
    const float* __restrict__ in, const float* __restrict__ w,
    const float* __restrict__ cb, const float* __restrict__ bng,
    const float* __restrict__ bnb, const float* __restrict__ bnm,
    const float* __restrict__ bnv,
    f16* __restrict__ out_hi, f16* __restrict__ out_lo)
{
    __shared__ float smem[3 * 34 * 34];
    const int tid = threadIdx.x;
    const int cob = blockIdx.x;      // 0..1 (16 co each)
    const int tile = blockIdx.y;     // 0..3 (32x32 tiles)
    const int b = blockIdx.z;        // local batch
    const int ty0 = (tile >> 1) * 32, tx0 = (tile & 1) * 32;
    const int tx = tid & 15, ty = tid >> 4;

    float acc[16][4];
#pragma unroll
    for (int i = 0; i < 16; ++i) acc[i][0] = acc[i][1] = acc[i][2] = acc[i][3] = 0.f;

    for (int i = tid; i < 3 * 34 * 34; i += 256) {
        int ci = i / 1156;
        int rem = i - ci * 1156;
        int rr = rem / 34, cc = rem - rr * 34;
        int gy = ty0 + rr - 1, gx = tx0 + cc - 1;
        float v = 0.f;
        if (gy >= 0 && gy < 64 && gx >= 0 && gx < 64)
            v = in[((size_t)(b * 3 + ci) * 64 + gy) * 64 + gx];
        smem[i] = v;
    }
    __syncthreads();

#pragma unroll
    for (int ci = 0; ci < 3; ++ci) {
        float p[4][4];
        const float* sp = smem + ci * 1156 + (2 * ty) * 34 + 2 * tx;
#pragma unroll
        for (int rr = 0; rr < 4; ++rr)
#pragma unroll
            for (int cc2 = 0; cc2 < 4; ++cc2)
                p[rr][cc2] = sp[rr * 34 + cc2];
        const float* wp = w + ((size_t)(cob * 16) * 3 + ci) * 9;
#pragma unroll
        for (int co = 0; co < 16; ++co) {
            const float* wc = wp + (size_t)co * 27;
#pragma unroll
            for (int ky = 0; ky < 3; ++ky)
#pragma unroll
                for (int kx = 0; kx < 3; ++kx) {
                    float wv = wc[ky * 3 + kx];
                    acc[co][0] = fmaf(wv, p[ky][kx],         acc[co][0]);
                    acc[co][1] = fmaf(wv, p[ky][kx + 1],     acc[co][1]);
                    acc[co][2] = fmaf(wv, p[ky + 1][kx],     acc[co][2]);
                    acc[co][3] = fmaf(wv, p[ky + 1][kx + 1], acc[co][3]);
                }
        }
    }

    float scale[16], bias2[16];
#pragma unroll
    for (int co = 0; co < 16; ++co) {
        int cog = cob * 16 + co;
        scale[co] = bng[cog] / sqrtf(bnv[cog] + 1e-5f);
        bias2[co] = (cb[cog] - bnm[cog]) * scale[co] + bnb[cog];
    }
#pragma unroll
    for (int p2 = 0; p2 < 4; ++p2) {
        int gy = ty0 + 2 * ty + (p2 >> 1);
        int gx = tx0 + 2 * tx + (p2 & 1);
        half8 hv0 = {}, hv1 = {}, lv0 = {}, lv1 = {};
#pragma unroll
        for (int co = 0; co < 16; ++co) {
            float v = fmaxf(fmaf(acc[co][p2], scale[co], bias2[co]), 0.f);
            f16 h = (f16)v;
            f16 l2 = (f16)(v - (float)h);
            if (co < 8) { hv0[co] = h; lv0[co] = l2; }
            else        { hv1[co - 8] = h; lv1[co - 8] = l2; }
        }
        size_t base = (((size_t)b * 64 + gy) * 64 + gx) * 32 + cob * 16;
        *reinterpret_cast<half8*>(&out_hi[base]) = hv0;
        *reinterpret_cast<half8*>(&out_hi[base + 8]) = hv1;
        *reinterpret_cast<half8*>(&out_lo[base]) = lv0;
        *reinterpret_cast<half8*>(&out_lo[base + 8]) = lv1;
    }
}

// ---------------------------------------------------------------------------
// Weight prep: fold BN scale, decompose to f16 hi/lo in B-fragment lane order
// W_pre[cig][s][cof][lane][8]:  ci = cig*32+(lane>>4)*8+j, co = cof*16+(lane&15)
// ---------------------------------------------------------------------------
template<int CI, int CO>
__global__ __launch_bounds__(256) void prep_weights(
    const float* __restrict__ w, const float* __restrict__ cb,
    const float* __restrict__ bng, const float* __restrict__ bnb,
    const float* __restrict__ bnm, const float* __restrict__ bnv,
    f16* __restrict__ wh, f16* __restrict__ wl, float* __restrict__ bias2)
{
    const int idx = blockIdx.x * 256 + threadIdx.x;
    constexpr int COF = CO / 16;
    constexpr int TOT = (CI / 32) * 9 * COF * 64;
    if (idx < CO) {
        float sc = bng[idx] / sqrtf(bnv[idx] + 1e-5f);
        bias2[idx] = (cb[idx] - bnm[idx]) * sc + bnb[idx];
    }
    if (idx >= TOT) return;
    const int l = idx & 63;
    int r = idx >> 6;
    const int cof = r % COF; r /= COF;
    const int s = r % 9; r /= 9;
    const int cig = r;
    const int co = cof * 16 + (l & 15);
    const float sc = bng[co] / sqrtf(bnv[co] + 1e-5f);
    const int cib = cig * 32 + (l >> 4) * 8;
#pragma unroll
    for (int j = 0; j < 8; ++j) {
        const int ci = cib + j;
        float v = w[((size_t)co * CI + ci) * 9 + s] * sc;
        f16 h = (f16)v;
        wh[(size_t)idx * 8 + j] = h;
        wl[(size_t)idx * 8 + j] = (f16)(v - (float)h);
    }
}

// ---------------------------------------------------------------------------
// MFMA conv: 3x3 pad1, fp16-split (3 products), fused bias+ReLU(+pool/+mean).
// Block: 16 rows x 32 cols pixels, 64 co; 8 waves (wave = 2 rows x 32 cols).
// LDS halo [plane][g][18][34][8ci], PART=4904 f16 -> bank rot {0,20,8,28}.
// 78.4 KB LDS -> 2 blocks/CU resident -> 4 waves/SIMD.
// ---------------------------------------------------------------------------
template<int CI, int CO, int HWI, bool POOL, bool MEAN>
__global__ __launch_bounds__(512, 4) void conv_mfma(
    const f16* __restrict__ in_hi, const f16* __restrict__ in_lo,
    const f16* __restrict__ wh, const f16* __restrict__ wl,
    const float* __restrict__ bias2,
    f16* __restrict__ out_hi, f16* __restrict__ out_lo,
    float* __restrict__ feats)
{
    constexpr int XSEG = HWI / 32;
    constexpr int CIG = CI / 32;
    constexpr int COF = CO / 16;
    constexpr int PART = 4904;            // 18*34*8 + 8 pad (f16): bank rot {0,20,8,28}
    constexpr int HALO_PX = 18 * 34;      // 612
    constexpr int NTASK = 2 * 4 * HALO_PX; // 4896 half8 staging tasks
    __shared__ alignas(16) f16 lds[2 * 4 * PART];

    const int tid = threadIdx.x;
    const int wave = tid >> 6;            // 0..7
    const int lane = tid & 63;
    const int l15 = lane & 15, lg = lane >> 4;
    const int cof0 = blockIdx.x * 4;
    const int tile = blockIdx.y;
    const int b = blockIdx.z;
    const int ty0 = (tile / XSEG) * 16;
    const int x0 = (tile % XSEG) * 32;

    const f32x4v zero4 = {0.f, 0.f, 0.f, 0.f};
    f32x4v acc[4][4];
#pragma unroll
    for (int m = 0; m < 4; ++m)
#pragma unroll
        for (int cf = 0; cf < 4; ++cf) acc[m][cf] = zero4;

    for (int cig = 0; cig < CIG; ++cig) {
        __syncthreads();
        // stage 18x34 halo, 32 ci, hi+lo planes (tasks: plane, g, pixel)
        for (int task = tid; task < NTASK; task += 512) {
            int plane = (task >= NTASK / 2) ? 1 : 0;
            int r = task - plane * (NTASK / 2);
            int g = r & 3, p = r >> 2;
            int yy = p / 34, xx = p - yy * 34;
            int gy = ty0 + yy - 1, gx = x0 + xx - 1;
            half8 v = {};
            if (gy >= 0 && gy < HWI && gx >= 0 && gx < HWI) {
                const f16* src = (plane ? in_lo : in_hi)
                    + (((size_t)b * HWI + gy) * HWI + gx) * CI + cig * 32 + g * 8;
                v = *reinterpret_cast<const half8*>(src);
            }
            *reinterpret_cast<half8*>(&lds[(plane * 4 + g) * PART + p * 8]) = v;
        }
        __syncthreads();

#pragma unroll
        for (int ky = 0; ky < 3; ++ky) {
#pragma unroll
            for (int kx = 0; kx < 3; ++kx) {
                const int s = ky * 3 + kx;
                half8 Ah[4], Al[4];
#pragma unroll
                for (int dr = 0; dr < 2; ++dr)
#pragma unroll
                    for (int xs = 0; xs < 2; ++xs) {
                        int yy = 2 * wave + dr + ky;
                        int xx = xs * 16 + l15 + kx;
                        int off = (yy * 34 + xx) * 8;
                        Ah[dr * 2 + xs] = *reinterpret_cast<const half8*>(&lds[lg * PART + off]);
                        Al[dr * 2 + xs] = *reinterpret_cast<const half8*>(&lds[(4 + lg) * PART + off]);
                    }
                const size_t wb = ((((size_t)cig * 9 + s) * COF + cof0) * 64 + lane) * 8;
                __builtin_amdgcn_s_setprio(1);
#pragma unroll
                for (int cf = 0; cf < 4; ++cf) {
                    half8 Bh = *reinterpret_cast<const half8*>(&wh[wb + (size_t)cf * 512]);
                    half8 Bl = *reinterpret_cast<const half8*>(&wl[wb + (size_t)cf * 512]);
#pragma unroll
                    for (int m = 0; m < 4; ++m) {
                        acc[m][cf] = __builtin_amdgcn_mfma_f32_16x16x32_f16(Ah[m], Bh, acc[m][cf], 0, 0, 0);
                        acc[m][cf] = __builtin_amdgcn_mfma_f32_16x16x32_f16(Ah[m], Bl, acc[m][cf], 0, 0, 0);
                        acc[m][cf] = __builtin_amdgcn_mfma_f32_16x16x32_f16(Al[m], Bh, acc[m][cf], 0, 0, 0);
                    }
                }
                __builtin_amdgcn_s_setprio(0);
            }
        }
    }

    // epilogue. D layout: col(co)=lane&15, row(pixel-x)=(lane>>4)*4+reg
    if (!POOL) {
#pragma unroll
        for (int cf = 0; cf < 4; ++cf) {
            const int co = (cof0 + cf) * 16 + l15;
            const float bs = bias2[co];
#pragma unroll
            for (int dr = 0; dr < 2; ++dr) {
                const int y = ty0 + 2 * wave + dr;
#pragma unroll
                for (int xs = 0; xs < 2; ++xs) {
#pragma unroll
                    for (int rg = 0; rg < 4; ++rg) {
                        const int xg = x0 + xs * 16 + lg * 4 + rg;
                        float v = fmaxf(acc[dr * 2 + xs][cf][rg] + bs, 0.f);
                        f16 h = (f16)v;
                        f16 l2 = (f16)(v - (float)h);
                        size_t idx = (((size_t)b * HWI + y) * HWI + xg) * CO + co;
                        out_hi[idx] = h;
                        out_lo[idx] = l2;
                    }
                }
            }
        }
    } else {
        float msum[4] = {0.f, 0.f, 0.f, 0.f};
        const int HP = HWI / 2;
        const int yp = (ty0 >> 1) + wave;
#pragma unroll
        for (int cf = 0; cf < 4; ++cf) {
            const int co = (cof0 + cf) * 16 + l15;
            const float bs = bias2[co];
#pragma unroll
            for (int xs = 0; xs < 2; ++xs) {
#pragma unroll
                for (int p = 0; p < 2; ++p) {
                    float v00 = fmaxf(acc[xs][cf][2 * p]         + bs, 0.f);
                    float v01 = fmaxf(acc[xs][cf][2 * p + 1]     + bs, 0.f);
                    float v10 = fmaxf(acc[2 + xs][cf][2 * p]     + bs, 0.f);
                    float v11 = fmaxf(acc[2 + xs][cf][2 * p + 1] + bs, 0.f);
                    float pv = fmaxf(fmaxf(v00, v01), fmaxf(v10, v11));
                    if (MEAN) {
                        msum[cf] += pv;
                    } else {
                        const int xp = (x0 >> 1) + xs * 8 + lg * 2 + p;
                        f16 h = (f16)pv;
                        f16 l2 = (f16)(pv - (float)h);
                        size_t idx = (((size_t)b * HP + yp) * HP + xp) * CO + co;
                        out_hi[idx] = h;
                        out_lo[idx] = l2;
                    }
                }
            }
        }
        if (MEAN) {
#pragma unroll
            for (int cf = 0; cf < 4; ++cf) {
                float sv = msum[cf];
                sv += __shfl_xor(sv, 16);
                sv += __shfl_xor(sv, 32);
                if (lg == 0) {
                    const int co = (cof0 + cf) * 16 + l15;
                    atomicAdd(&feats[b * 256 + co], sv * (1.f / 256.f));
                }
            }
        }
    }
}

// ---------------------------------------------------------------------------
// Head (unchanged, verified)
// ---------------------------------------------------------------------------
__global__ __launch_bounds__(256) void gemm_logits(
    const float* __restrict__ F, const float* __restrict__ Wm,
    const float* __restrict__ bias, float* __restrict__ L)
{
    __shared__ alignas(16) float As[16][68];
    __shared__ alignas(16) float Bs[16][68];
    const int tid = threadIdx.x;
    const int n0 = blockIdx.x * 64, m0 = blockIdx.y * 64;
    const int tc = tid & 15, tr = tid >> 4;
    float acc[4][4] = {};

    for (int k0 = 0; k0 < 256; k0 += 16) {
        __syncthreads();
#pragma unroll
        for (int l = 0; l < 4; ++l) {
            int idx = l * 256 + tid;
            int k = idx & 15, m = idx >> 4;
            As[k][m] = F[(size_t)(m0 + m) * 256 + k0 + k];
            Bs[k][m] = Wm[(size_t)(n0 + m) * 256 + k0 + k];
        }
        __syncthreads();
#pragma unroll
        for (int k = 0; k < 16; ++k) {
            float4 a  = *reinterpret_cast<const float4*>(&As[k][tr * 4]);
            float4 bb = *reinterpret_cast<const float4*>(&Bs[k][tc * 4]);
            float av[4] = {a.x, a.y, a.z, a.w};
            float bv[4] = {bb.x, bb.y, bb.z, bb.w};
#pragma unroll
            for (int i = 0; i < 4; ++i)
#pragma unroll
                for (int j = 0; j < 4; ++j)
                    acc[i][j] = fmaf(av[i], bv[j], acc[i][j]);
        }
    }
    float4 bs = *reinterpret_cast<const float4*>(&bias[n0 + tc * 4]);
    float bvv[4] = {bs.x, bs.y, bs.z, bs.w};
#pragma unroll
    for (int i = 0; i < 4; ++i) {
        int m = m0 + tr * 4 + i;
        float4 o;
        o.x = acc[i][0] + bvv[0];
        o.y = acc[i][1] + bvv[1];
        o.z = acc[i][2] + bvv[2];
        o.w = acc[i][3] + bvv[3];
        *reinterpret_cast<float4*>(&L[(size_t)m * 16000 + n0 + tc * 4]) = o;
    }
}

__global__ __launch_bounds__(256) void softmax_ent(
    const float* __restrict__ L, float* __restrict__ conf)
{
    const int row = blockIdx.x;
    const float* l = L + (size_t)row * 1000;
    const int tid = threadIdx.x;
    const int lane = tid & 63, wid = tid >> 6;
    __shared__ float r1[4], r2[4];

    float m = -3.402823466e38f;
    for (int i = tid; i < 1000; i += 256) m = fmaxf(m, l[i]);
#pragma unroll
    for (int s = 32; s >= 1; s >>= 1) m = fmaxf(m, __shfl_xor(m, s));
    if (lane == 0) r1[wid] = m;
    __syncthreads();
    m = fmaxf(fmaxf(r1[0], r1[1]), fmaxf(r1[2], r1[3]));
    __syncthreads();

    float s1 = 0.f, s2 = 0.f;
    for (int i = tid; i < 1000; i += 256) {
        float d = l[i] - m;
        float e = expf(d);
        s1 += e;
        s2 += d * e;
    }
#pragma unroll
    for (int s = 32; s >= 1; s >>= 1) { s1 += __shfl_xor(s1, s); s2 += __shfl_xor(s2, s); }
    if (lane == 0) { r1[wid] = s1; r2[wid] = s2; }
    __syncthreads();
    if (tid == 0) {
        float S1 = r1[0] + r1[1] + r1[2] + r1[3];
        float S2 = r2[0] + r2[1] + r2[2] + r2[3];
        conf[row] = S2 / S1 - logf(S1);
    }
}

__global__ __launch_bounds__(128) void gate_kernel(
    const float* __restrict__ F, const float* __restrict__ w1,
    const float* __restrict__ b1, const float* __restrict__ w2,
    const float* __restrict__ b2, const float* __restrict__ conf,
    float* __restrict__ rs_ws, float* __restrict__ rs_out)
{
    const int b = blockIdx.x, j = threadIdx.x;
    __shared__ float fl[256], g[128];
    fl[j] = F[b * 256 + j];
    fl[j + 128] = F[b * 256 + 128 + j];
    __syncthreads();
    float s = b1[j];
    const float* wr = w1 + (size_t)j * 256;
    for (int d = 0; d < 256; ++d) s = fmaf(fl[d], wr[d], s);
    g[j] = fmaxf(s, 0.f);
    __syncthreads();
    if (j < 16) {
        float t = b2[j];
        const float* w2r = w2 + (size_t)j * 128;
        for (int q = 0; q < 128; ++q) t = fmaf(g[q], w2r[q], t);
        float r = t * conf[b * 16 + j];
        rs_ws[b * 16 + j] = r;
        rs_out[b * 16 + j] = r;
    }
}

__global__ __launch_bounds__(512) void capacity_topk(
    const float* __restrict__ rs, unsigned char* __restrict__ Dcap)
{
    const int e = blockIdx.x, t = threadIdx.x;
    __shared__ unsigned long long keys[512];
    float v = rs[t * 16 + e];
    unsigned u = __float_as_uint(v);
    u = (u & 0x80000000u) ? ~u : (u | 0x80000000u);
    keys[t] = ((unsigned long long)u << 32) | (unsigned long long)(511 - t);
    Dcap[t * 16 + e] = 0;
    __syncthreads();
    for (int k = 2; k <= 512; k <<= 1) {
        for (int j = k >> 1; j > 0; j >>= 1) {
            int ixj = t ^ j;
            if (ixj > t) {
                unsigned long long a = keys[t], c = keys[ixj];
                bool up = ((t & k) == 0);
                bool sw = up ? (a < c) : (a > c);
                if (sw) { keys[t] = c; keys[ixj] = a; }
            }
            __syncthreads();
        }
    }
    if (t < 128) {
        int idx = 511 - (int)(keys[t] & 0xFFFFFFFFu);
        Dcap[idx * 16 + e] = 1;
    }
}

__global__ __launch_bounds__(256) void token_topk(
    const float* __restrict__ rs, const unsigned char* __restrict__ Dcap,
    int* __restrict__ sel, float* __restrict__ selw, float* __restrict__ D_out)
{
    int b = blockIdx.x * 256 + threadIdx.x;
    if (b >= 512) return;
    float best1 = -3.402823466e38f, best2 = -3.402823466e38f;
    int i1 = 0, i2 = 1;
#pragma unroll
    for (int e = 0; e < 16; ++e) {
        float v = Dcap[b * 16 + e] ? rs[b * 16 + e] : -1e9f;
        if (v > best1) { best2 = best1; i2 = i1; best1 = v; i1 = e; }
        else if (v > best2) { best2 = v; i2 = e; }
    }
#pragma unroll
    for (int e = 0; e < 16; ++e)
        D_out[b * 16 + e] = (e == i1 || e == i2) ? 1.0f : 0.0f;
    sel[2 * b] = i1;
    sel[2 * b + 1] = i2;
    selw[2 * b] = rs[b * 16 + i1];
    selw[2 * b + 1] = rs[b * 16 + i2];
}

__global__ __launch_bounds__(256) void combine_kernel(
    const float* __restrict__ L, const int* __restrict__ sel,
    const float* __restrict__ selw, float* __restrict__ outF)
{
    int b = blockIdx.y;
    int c = blockIdx.x * 256 + threadIdx.x;
    if (c >= 1000) return;
    int i1 = sel[2 * b], i2 = sel[2 * b + 1];
    float w1 = selw[2 * b], w2 = selw[2 * b + 1];
    const float* lb = L + (size_t)b * 16000;
    outF[b * 1000 + c] = (w1 * lb[i1 * 1000 + c] + w2 * lb[i2 * 1000 + c]) * 0.5f;
}

// ---------------------------------------------------------------------------
extern "C" void kernel_launch(void* const* d_in, const int* in_sizes, int n_in,
                              void* d_out, int out_size, void* d_ws, size_t ws_size,
                              hipStream_t stream)
{
    const float* x = (const float*)d_in[0];
    const float *cw[4], *cbv[4], *bg[4], *bb[4], *bm[4], *bv[4];
    for (int i = 0; i < 4; ++i) {
        cw[i]  = (const float*)d_in[1 + 6 * i + 0];
        cbv[i] = (const float*)d_in[1 + 6 * i + 1];
        bg[i]  = (const float*)d_in[1 + 6 * i + 2];
        bb[i]  = (const float*)d_in[1 + 6 * i + 3];
        bm[i]  = (const float*)d_in[1 + 6 * i + 4];
        bv[i]  = (const float*)d_in[1 + 6 * i + 5];
    }
    const float* gw1 = (const float*)d_in[25];
    const float* gb1 = (const float*)d_in[26];
    const float* gw2 = (const float*)d_in[27];
    const float* gb2 = (const float*)d_in[28];
    const float* clw = (const float*)d_in[29];
    const float* clb = (const float*)d_in[30];

    char* wsb = (char*)d_ws;
    f16* a1h = (f16*)(wsb + 0);
    f16* a1l = (f16*)(wsb + 16777216);
    f16* a2h = (f16*)(wsb + 33554432);
    f16* a2l = (f16*)(wsb + 41943040);
    f16* W2h = (f16*)(wsb + 50331648);
    f16* W2l = (f16*)(wsb + 50368512);
    f16* W3h = (f16*)(wsb + 50405376);
    f16* W3l = (f16*)(wsb + 50552832);
    f16* W4h = (f16*)(wsb + 50700288);
    f16* W4l = (f16*)(wsb + 51290112);
    float* B2 = (float*)(wsb + 51879936);
    float* B3 = (float*)(wsb + 51880192);
    float* B4 = (float*)(wsb + 51880704);
    float* feats  = (float*)(wsb + 51881728);
    float* logits = (float*)(wsb + 52406016);
    float* conf   = (float*)(wsb + 85174016);
    float* rs     = (float*)(wsb + 85206784);
    unsigned char* Dcap = (unsigned char*)(wsb + 85239552);
    int*   sel  = (int*)(wsb + 85247744);
    float* selw = (float*)(wsb + 85251840);
    f16* a3h = a1h;
    f16* a3l = a1l;

    float* outF  = (float*)d_out;
    float* outRS = outF + 512 * 1000;
    float* outD  = outRS + 512 * 16;

    hipMemsetAsync(feats, 0, 512 * 256 * sizeof(float), stream);
    hipLaunchKernelGGL((prep_weights<32, 64>), dim3(9), dim3(256), 0, stream,
                       cw[1], cbv[1], bg[1], bb[1], bm[1], bv[1], W2h, W2l, B2);
    hipLaunchKernelGGL((prep_weights<64, 128>), dim3(36), dim3(256), 0, stream,
                       cw[2], cbv[2], bg[2], bb[2], bm[2], bv[2], W3h, W3l, B3);
    hipLaunchKernelGGL((prep_weights<128, 256>), dim3(144), dim3(256), 0, stream,
                       cw[3], cbv[3], bg[3], bb[3], bm[3], bv[3], W4h, W4l, B4);

    for (int c = 0; c < 8; ++c) {
        const float* xin = x + (size_t)c * 64 * 3 * 64 * 64;
        hipLaunchKernelGGL(conv1_kernel, dim3(2, 4, 64), dim3(256), 0, stream,
                           xin, cw[0], cbv[0], bg[0], bb[0], bm[0], bv[0], a1h, a1l);
        hipLaunchKernelGGL((conv_mfma<32, 64, 64, true, false>),
                           dim3(1, 8, 64), dim3(512), 0, stream,
                           a1h, a1l, W2h, W2l, B2, a2h, a2l, (float*)nullptr);
        hipLaunchKernelGGL((conv_mfma<64, 128, 32, false, false>),
                           dim3(2, 2, 64), dim3(512), 0, stream,
                           a2h, a2l, W3h, W3l, B3, a3h, a3l, (float*)nullptr);
        hipLaunchKernelGGL((conv_mfma<128, 256, 32, true, true>),
                           dim3(4, 2, 64), dim3(512), 0, stream,
                           a3h, a3l, W4h, W4l, B4, (f16*)nullptr, (f16*)nullptr,
                           feats + (size_t)c * 64 * 256);
    }

    hipLaunchKernelGGL(gemm_logits, dim3(250, 8), dim3(256), 0, stream,
                       feats, clw, clb, logits);
    hipLaunchKernelGGL(softmax_ent, dim3(8192), dim3(256), 0, stream, logits, conf);
    hipLaunchKernelGGL(gate_kernel, dim3(512), dim3(128), 0, stream,
                       feats, gw1, gb1, gw2, gb2, conf, rs, outRS);
    hipLaunchKernelGGL(capacity_topk, dim3(16), dim3(512), 0, stream, rs, Dcap);
    hipLaunchKernelGGL(token_topk, dim3(2), dim3(256), 0, stream,
                       rs, Dcap, sel, selw, outD);
    hipLaunchKernelGGL(combine_kernel, dim3(4, 512), dim3(256), 0, stream,
                       logits, sel, selw, outF);
}

// Round 11
// 1711.936 us; speedup vs baseline: 1.1666x; 1.1666x over previous
//
#include <hip/hip_runtime.h>
#include <hip/hip_bf16.h>
#include <math.h>

// B=512, H=W=64, E=16, K=2, CAP=128, TC=256, NC=1000
// Outputs: final_logits[512,1000], routing_scores[512,16], D[512,16] (fp32)
//
// conv2/3/4: implicit-GEMM MFMA, fp16 two-term split (3 MFMAs / fp32 product).
// R6 @1924us: conv4 MfmaUtil 42%, occ 20.5%. R7 (8 waves/block) @1997us:
// occ 38% but MfmaUtil STILL 42% -> not wave-starved; staging-serialized.
// conv4 FETCH 158MB == 512blk*4cig*78KB: the 4 cof-blocks sharing one tile
// refetch the halo from HBM 4x (consecutive block ids -> different XCDs).
// R8 change: bijective XCD swizzle so cof-blocks + 8 consecutive b's land on
// one XCD (2.1MB working set < 4MB XCD L2) -> halo fetched once per XCD.

typedef _Float16 f16;
typedef f16 half8 __attribute__((ext_vector_type(8)));
typedef float f32x4v __attribute__((ext_vector_type(4)));

// ---------------------------------------------------------------------------
// conv1: 3->32, 64x64, vector fp32, epilogue writes NHWC f16 hi/lo planes.
// ---------------------------------------------------------------------------
__global__ __launch_bounds__(256) void conv1_kernel(
    const float* __restrict__ in, const float* __restrict__ w,
    const float* __restrict__ cb, const float* __restrict__ bng,
    const float* __restrict__ bnb, const float* __restrict__ bnm,
    const float* __restrict__ bnv,
    f16* __restrict__ out_hi, f16* __restrict__ out_lo)
{
    __shared__ float smem[3 * 34 * 34];
    const int tid = threadIdx.x;
    const int cob = blockIdx.x;      // 0..1 (16 co each)
    const int tile = blockIdx.y;     // 0..3 (32x32 tiles)
    const int b = blockIdx.z;        // local batch
    const int ty0 = (tile >> 1) * 32, tx0 = (tile & 1) * 32;
    const int tx = tid & 15, ty = tid >> 4;

    float acc[16][4];
#pragma unroll
    for (int i = 0; i < 16; ++i) acc[i][0] = acc[i][1] = acc[i][2] = acc[i][3] = 0.f;

    for (int i = tid; i < 3 * 34 * 34; i += 256) {
        int ci = i / 1156;
        int rem = i - ci * 1156;
        int rr = rem / 34, cc = rem - rr * 34;
        int gy = ty0 + rr - 1, gx = tx0 + cc - 1;
        float v = 0.f;
        if (gy >= 0 && gy < 64 && gx >= 0 && gx < 64)
            v = in[((size_t)(b * 3 + ci) * 64 + gy) * 64 + gx];
        smem[i] = v;
    }
    __syncthreads();

#pragma unroll
    for (int ci = 0; ci < 3; ++ci) {
        float p[4][4];
        const float* sp = smem + ci * 1156 + (2 * ty) * 34 + 2 * tx;
#pragma unroll
        for (int rr = 0; rr < 4; ++rr)
#pragma unroll
            for (int cc2 = 0; cc2 < 4; ++cc2)
                p[rr][cc2] = sp[rr * 34 + cc2];
        const float* wp = w + ((size_t)(cob * 16) * 3 + ci) * 9;
#pragma unroll
        for (int co = 0; co < 16; ++co) {
            const float* wc = wp + (size_t)co * 27;
#pragma unroll
            for (int ky = 0; ky < 3; ++ky)
#pragma unroll
                for (int kx = 0; kx < 3; ++kx) {
                    float wv = wc[ky * 3 + kx];
                    acc[co][0] = fmaf(wv, p[ky][kx],         acc[co][0]);
                    acc[co][1] = fmaf(wv, p[ky][kx + 1],     acc[co][1]);
                    acc[co][2] = fmaf(wv, p[ky + 1][kx],     acc[co][2]);
                    acc[co][3] = fmaf(wv, p[ky + 1][kx + 1], acc[co][3]);
                }
        }
    }

    float scale[16], bias2[16];
#pragma unroll
    for (int co = 0; co < 16; ++co) {
        int cog = cob * 16 + co;
        scale[co] = bng[cog] / sqrtf(bnv[cog] + 1e-5f);
        bias2[co] = (cb[cog] - bnm[cog]) * scale[co] + bnb[cog];
    }
#pragma unroll
    for (int p2 = 0; p2 < 4; ++p2) {
        int gy = ty0 + 2 * ty + (p2 >> 1);
        int gx = tx0 + 2 * tx + (p2 & 1);
        half8 hv0 = {}, hv1 = {}, lv0 = {}, lv1 = {};
#pragma unroll
        for (int co = 0; co < 16; ++co) {
            float v = fmaxf(fmaf(acc[co][p2], scale[co], bias2[co]), 0.f);
            f16 h = (f16)v;
            f16 l2 = (f16)(v - (float)h);
            if (co < 8) { hv0[co] = h; lv0[co] = l2; }
            else        { hv1[co - 8] = h; lv1[co - 8] = l2; }
        }
        size_t base = (((size_t)b * 64 + gy) * 64 + gx) * 32 + cob * 16;
        *reinterpret_cast<half8*>(&out_hi[base]) = hv0;
        *reinterpret_cast<half8*>(&out_hi[base + 8]) = hv1;
        *reinterpret_cast<half8*>(&out_lo[base]) = lv0;
        *reinterpret_cast<half8*>(&out_lo[base + 8]) = lv1;
    }
}

// ---------------------------------------------------------------------------
// Weight prep: fold BN scale, decompose to f16 hi/lo in B-fragment lane order
// ---------------------------------------------------------------------------
template<int CI, int CO>
__global__ __launch_bounds__(256) void prep_weights(
    const float* __restrict__ w, const float* __restrict__ cb,
    const float* __restrict__ bng, const float* __restrict__ bnb,
    const float* __restrict__ bnm, const float* __restrict__ bnv,
    f16* __restrict__ wh, f16* __restrict__ wl, float* __restrict__ bias2)
{
    const int idx = blockIdx.x * 256 + threadIdx.x;
    constexpr int COF = CO / 16;
    constexpr int TOT = (CI / 32) * 9 * COF * 64;
    if (idx < CO) {
        float sc = bng[idx] / sqrtf(bnv[idx] + 1e-5f);
        bias2[idx] = (cb[idx] - bnm[idx]) * sc + bnb[idx];
    }
    if (idx >= TOT) return;
    const int l = idx & 63;
    int r = idx >> 6;
    const int cof = r % COF; r /= COF;
    const int s = r % 9; r /= 9;
    const int cig = r;
    const int co = cof * 16 + (l & 15);
    const float sc = bng[co] / sqrtf(bnv[co] + 1e-5f);
    const int cib = cig * 32 + (l >> 4) * 8;
#pragma unroll
    for (int j = 0; j < 8; ++j) {
        const int ci = cib + j;
        float v = w[((size_t)co * CI + ci) * 9 + s] * sc;
        f16 h = (f16)v;
        wh[(size_t)idx * 8 + j] = h;
        wl[(size_t)idx * 8 + j] = (f16)(v - (float)h);
    }
}

// ---------------------------------------------------------------------------
// MFMA conv: 3x3 pad1, fp16-split, fused bias+ReLU(+pool/+mean).
// Block: 16 rows x 32 cols pixels, 64 co; 8 waves. 1D grid + XCD swizzle:
// logical = (hw&7)*(nwg/8) + (hw>>3); cof-blocks of one tile + 8 consecutive
// b share an XCD -> halo L2-resident after first fetch.
// NXB = cof-blocks (CO/64), NTILES = pixel tiles per image.
// ---------------------------------------------------------------------------
template<int CI, int CO, int HWI, int NXB, int NTILES, bool POOL, bool MEAN>
__global__ __launch_bounds__(512, 4) void conv_mfma(
    const f16* __restrict__ in_hi, const f16* __restrict__ in_lo,
    const f16* __restrict__ wh, const f16* __restrict__ wl,
    const float* __restrict__ bias2,
    f16* __restrict__ out_hi, f16* __restrict__ out_lo,
    float* __restrict__ feats)
{
    constexpr int XSEG = HWI / 32;
    constexpr int CIG = CI / 32;
    constexpr int COF = CO / 16;
    constexpr int PART = 4904;            // 18*34*8 + 8 pad (f16)
    constexpr int HALO_PX = 18 * 34;      // 612
    constexpr int NTASK = 2 * 4 * HALO_PX;
    constexpr int NWG = NXB * NTILES * 64;
    __shared__ alignas(16) f16 lds[2 * 4 * PART];

    const int tid = threadIdx.x;
    const int wave = tid >> 6;
    const int lane = tid & 63;
    const int l15 = lane & 15, lg = lane >> 4;

    // bijective XCD swizzle (NWG % 8 == 0)
    const int hw = blockIdx.x;
    const int logical = (hw & 7) * (NWG >> 3) + (hw >> 3);
    const int cofb = logical % NXB;
    const int rem2 = logical / NXB;
    const int tile = rem2 % NTILES;
    const int b = rem2 / NTILES;
    const int cof0 = cofb * 4;
    const int ty0 = (tile / XSEG) * 16;
    const int x0 = (tile % XSEG) * 32;

    const f32x4v zero4 = {0.f, 0.f, 0.f, 0.f};
    f32x4v acc[4][4];
#pragma unroll
    for (int m = 0; m < 4; ++m)
#pragma unroll
        for (int cf = 0; cf < 4; ++cf) acc[m][cf] = zero4;

    for (int cig = 0; cig < CIG; ++cig) {
        __syncthreads();
        for (int task = tid; task < NTASK; task += 512) {
            int plane = (task >= NTASK / 2) ? 1 : 0;
            int r = task - plane * (NTASK / 2);
            int g = r & 3, p = r >> 2;
            int yy = p / 34, xx = p - yy * 34;
            int gy = ty0 + yy - 1, gx = x0 + xx - 1;
            half8 v = {};
            if (gy >= 0 && gy < HWI && gx >= 0 && gx < HWI) {
                const f16* src = (plane ? in_lo : in_hi)
                    + (((size_t)b * HWI + gy) * HWI + gx) * CI + cig * 32 + g * 8;
                v = *reinterpret_cast<const half8*>(src);
            }
            *reinterpret_cast<half8*>(&lds[(plane * 4 + g) * PART + p * 8]) = v;
        }
        __syncthreads();

#pragma unroll
        for (int ky = 0; ky < 3; ++ky) {
#pragma unroll
            for (int kx = 0; kx < 3; ++kx) {
                const int s = ky * 3 + kx;
                half8 Ah[4], Al[4];
#pragma unroll
                for (int dr = 0; dr < 2; ++dr)
#pragma unroll
                    for (int xs = 0; xs < 2; ++xs) {
                        int yy = 2 * wave + dr + ky;
                        int xx = xs * 16 + l15 + kx;
                        int off = (yy * 34 + xx) * 8;
                        Ah[dr * 2 + xs] = *reinterpret_cast<const half8*>(&lds[lg * PART + off]);
                        Al[dr * 2 + xs] = *reinterpret_cast<const half8*>(&lds[(4 + lg) * PART + off]);
                    }
                const size_t wb = ((((size_t)cig * 9 + s) * COF + cof0) * 64 + lane) * 8;
                __builtin_amdgcn_s_setprio(1);
#pragma unroll
                for (int cf = 0; cf < 4; ++cf) {
                    half8 Bh = *reinterpret_cast<const half8*>(&wh[wb + (size_t)cf * 512]);
                    half8 Bl = *reinterpret_cast<const half8*>(&wl[wb + (size_t)cf * 512]);
#pragma unroll
                    for (int m = 0; m < 4; ++m) {
                        acc[m][cf] = __builtin_amdgcn_mfma_f32_16x16x32_f16(Ah[m], Bh, acc[m][cf], 0, 0, 0);
                        acc[m][cf] = __builtin_amdgcn_mfma_f32_16x16x32_f16(Ah[m], Bl, acc[m][cf], 0, 0, 0);
                        acc[m][cf] = __builtin_amdgcn_mfma_f32_16x16x32_f16(Al[m], Bh, acc[m][cf], 0, 0, 0);
                    }
                }
                __builtin_amdgcn_s_setprio(0);
            }
        }
    }

    // epilogue. D layout: col(co)=lane&15, row(pixel-x)=(lane>>4)*4+reg
    if (!POOL) {
#pragma unroll
        for (int cf = 0; cf < 4; ++cf) {
            const int co = (cof0 + cf) * 16 + l15;
            const float bs = bias2[co];
#pragma unroll
            for (int dr = 0; dr < 2; ++dr) {
                const int y = ty0 + 2 * wave + dr;
#pragma unroll
                for (int xs = 0; xs < 2; ++xs) {
#pragma unroll
                    for (int rg = 0; rg < 4; ++rg) {
                        const int xg = x0 + xs * 16 + lg * 4 + rg;
                        float v = fmaxf(acc[dr * 2 + xs][cf][rg] + bs, 0.f);
                        f16 h = (f16)v;
                        f16 l2 = (f16)(v - (float)h);
                        size_t idx = (((size_t)b * HWI + y) * HWI + xg) * CO + co;
                        out_hi[idx] = h;
                        out_lo[idx] = l2;
                    }
                }
            }
        }
    } else {
        float msum[4] = {0.f, 0.f, 0.f, 0.f};
        const int HP = HWI / 2;
        const int yp = (ty0 >> 1) + wave;
#pragma unroll
        for (int cf = 0; cf < 4; ++cf) {
            const int co = (cof0 + cf) * 16 + l15;
            const float bs = bias2[co];
#pragma unroll
            for (int xs = 0; xs < 2; ++xs) {
#pragma unroll
                for (int p = 0; p < 2; ++p) {
                    float v00 = fmaxf(acc[xs][cf][2 * p]         + bs, 0.f);
                    float v01 = fmaxf(acc[xs][cf][2 * p + 1]     + bs, 0.f);
                    float v10 = fmaxf(acc[2 + xs][cf][2 * p]     + bs, 0.f);
                    float v11 = fmaxf(acc[2 + xs][cf][2 * p + 1] + bs, 0.f);
                    float pv = fmaxf(fmaxf(v00, v01), fmaxf(v10, v11));
                    if (MEAN) {
                        msum[cf] += pv;
                    } else {
                        const int xp = (x0 >> 1) + xs * 8 + lg * 2 + p;
                        f16 h = (f16)pv;
                        f16 l2 = (f16)(pv - (float)h);
                        size_t idx = (((size_t)b * HP + yp) * HP + xp) * CO + co;
                        out_hi[idx] = h;
                        out_lo[idx] = l2;
                    }
                }
            }
        }
        if (MEAN) {
#pragma unroll
            for (int cf = 0; cf < 4; ++cf) {
                float sv = msum[cf];
                sv += __shfl_xor(sv, 16);
                sv += __shfl_xor(sv, 32);
                if (lg == 0) {
                    const int co = (cof0 + cf) * 16 + l15;
                    atomicAdd(&feats[b * 256 + co], sv * (1.f / 256.f));
                }
            }
        }
    }
}

// ---------------------------------------------------------------------------
// Head (unchanged, verified)
// ---------------------------------------------------------------------------
__global__ __launch_bounds__(256) void gemm_logits(
    const float* __restrict__ F, const float* __restrict__ Wm,
    const float* __restrict__ bias, float* __restrict__ L)
{
    __shared__ alignas(16) float As[16][68];
    __shared__ alignas(16) float Bs[16][68];
    const int tid = threadIdx.x;
    const int n0 = blockIdx.x * 64, m0 = blockIdx.y * 64;
    const int tc = tid & 15, tr = tid >> 4;
    float acc[4][4] = {};

    for (int k0 = 0; k0 < 256; k0 += 16) {
        __syncthreads();
#pragma unroll
        for (int l = 0; l < 4; ++l) {
            int idx = l * 256 + tid;
            int k = idx & 15, m = idx >> 4;
            As[k][m] = F[(size_t)(m0 + m) * 256 + k0 + k];
            Bs[k][m] = Wm[(size_t)(n0 + m) * 256 + k0 + k];
        }
        __syncthreads();
#pragma unroll
        for (int k = 0; k < 16; ++k) {
            float4 a  = *reinterpret_cast<const float4*>(&As[k][tr * 4]);
            float4 bb = *reinterpret_cast<const float4*>(&Bs[k][tc * 4]);
            float av[4] = {a.x, a.y, a.z, a.w};
            float bv[4] = {bb.x, bb.y, bb.z, bb.w};
#pragma unroll
            for (int i = 0; i < 4; ++i)
#pragma unroll
                for (int j = 0; j < 4; ++j)
                    acc[i][j] = fmaf(av[i], bv[j], acc[i][j]);
        }
    }
    float4 bs = *reinterpret_cast<const float4*>(&bias[n0 + tc * 4]);
    float bvv[4] = {bs.x, bs.y, bs.z, bs.w};
#pragma unroll
    for (int i = 0; i < 4; ++i) {
        int m = m0 + tr * 4 + i;
        float4 o;
        o.x = acc[i][0] + bvv[0];
        o.y = acc[i][1] + bvv[1];
        o.z = acc[i][2] + bvv[2];
        o.w = acc[i][3] + bvv[3];
        *reinterpret_cast<float4*>(&L[(size_t)m * 16000 + n0 + tc * 4]) = o;
    }
}

__global__ __launch_bounds__(256) void softmax_ent(
    const float* __restrict__ L, float* __restrict__ conf)
{
    const int row = blockIdx.x;
    const float* l = L + (size_t)row * 1000;
    const int tid = threadIdx.x;
    const int lane = tid & 63, wid = tid >> 6;
    __shared__ float r1[4], r2[4];

    float m = -3.402823466e38f;
    for (int i = tid; i < 1000; i += 256) m = fmaxf(m, l[i]);
#pragma unroll
    for (int s = 32; s >= 1; s >>= 1) m = fmaxf(m, __shfl_xor(m, s));
    if (lane == 0) r1[wid] = m;
    __syncthreads();
    m = fmaxf(fmaxf(r1[0], r1[1]), fmaxf(r1[2], r1[3]));
    __syncthreads();

    float s1 = 0.f, s2 = 0.f;
    for (int i = tid; i < 1000; i += 256) {
        float d = l[i] - m;
        float e = expf(d);
        s1 += e;
        s2 += d * e;
    }
#pragma unroll
    for (int s = 32; s >= 1; s >>= 1) { s1 += __shfl_xor(s1, s); s2 += __shfl_xor(s2, s); }
    if (lane == 0) { r1[wid] = s1; r2[wid] = s2; }
    __syncthreads();
    if (tid == 0) {
        float S1 = r1[0] + r1[1] + r1[2] + r1[3];
        float S2 = r2[0] + r2[1] + r2[2] + r2[3];
        conf[row] = S2 / S1 - logf(S1);
    }
}

__global__ __launch_bounds__(128) void gate_kernel(
    const float* __restrict__ F, const float* __restrict__ w1,
    const float* __restrict__ b1, const float* __restrict__ w2,
    const float* __restrict__ b2, const float* __restrict__ conf,
    float* __restrict__ rs_ws, float* __restrict__ rs_out)
{
    const int b = blockIdx.x, j = threadIdx.x;
    __shared__ float fl[256], g[128];
    fl[j] = F[b * 256 + j];
    fl[j + 128] = F[b * 256 + 128 + j];
    __syncthreads();
    float s = b1[j];
    const float* wr = w1 + (size_t)j * 256;
    for (int d = 0; d < 256; ++d) s = fmaf(fl[d], wr[d], s);
    g[j] = fmaxf(s, 0.f);
    __syncthreads();
    if (j < 16) {
        float t = b2[j];
        const float* w2r = w2 + (size_t)j * 128;
        for (int q = 0; q < 128; ++q) t = fmaf(g[q], w2r[q], t);
        float r = t * conf[b * 16 + j];
        rs_ws[b * 16 + j] = r;
        rs_out[b * 16 + j] = r;
    }
}

__global__ __launch_bounds__(512) void capacity_topk(
    const float* __restrict__ rs, unsigned char* __restrict__ Dcap)
{
    const int e = blockIdx.x, t = threadIdx.x;
    __shared__ unsigned long long keys[512];
    float v = rs[t * 16 + e];
    unsigned u = __float_as_uint(v);
    u = (u & 0x80000000u) ? ~u : (u | 0x80000000u);
    keys[t] = ((unsigned long long)u << 32) | (unsigned long long)(511 - t);
    Dcap[t * 16 + e] = 0;
    __syncthreads();
    for (int k = 2; k <= 512; k <<= 1) {
        for (int j = k >> 1; j > 0; j >>= 1) {
            int ixj = t ^ j;
            if (ixj > t) {
                unsigned long long a = keys[t], c = keys[ixj];
                bool up = ((t & k) == 0);
                bool sw = up ? (a < c) : (a > c);
                if (sw) { keys[t] = c; keys[ixj] = a; }
            }
            __syncthreads();
        }
    }
    if (t < 128) {
        int idx = 511 - (int)(keys[t] & 0xFFFFFFFFu);
        Dcap[idx * 16 + e] = 1;
    }
}

__global__ __launch_bounds__(256) void token_topk(
    const float* __restrict__ rs, const unsigned char* __restrict__ Dcap,
    int* __restrict__ sel, float* __restrict__ selw, float* __restrict__ D_out)
{
    int b = blockIdx.x * 256 + threadIdx.x;
    if (b >= 512) return;
    float best1 = -3.402823466e38f, best2 = -3.402823466e38f;
    int i1 = 0, i2 = 1;
#pragma unroll
    for (int e = 0; e < 16; ++e) {
        float v = Dcap[b * 16 + e] ? rs[b * 16 + e] : -1e9f;
        if (v > best1) { best2 = best1; i2 = i1; best1 = v; i1 = e; }
        else if (v > best2) { best2 = v; i2 = e; }
    }
#pragma unroll
    for (int e = 0; e < 16; ++e)
        D_out[b * 16 + e] = (e == i1 || e == i2) ? 1.0f : 0.0f;
    sel[2 * b] = i1;
    sel[2 * b + 1] = i2;
    selw[2 * b] = rs[b * 16 + i1];
    selw[2 * b + 1] = rs[b * 16 + i2];
}

__global__ __launch_bounds__(256) void combine_kernel(
    const float* __restrict__ L, const int* __restrict__ sel,
    const float* __restrict__ selw, float* __restrict__ outF)
{
    int b = blockIdx.y;
    int c = blockIdx.x * 256 + threadIdx.x;
    if (c >= 1000) return;
    int i1 = sel[2 * b], i2 = sel[2 * b + 1];
    float w1 = selw[2 * b], w2 = selw[2 * b + 1];
    const float* lb = L + (size_t)b * 16000;
    outF[b * 1000 + c] = (w1 * lb[i1 * 1000 + c] + w2 * lb[i2 * 1000 + c]) * 0.5f;
}

// ---------------------------------------------------------------------------
extern "C" void kernel_launch(void* const* d_in, const int* in_sizes, int n_in,
                              void* d_out, int out_size, void* d_ws, size_t ws_size,
                              hipStream_t stream)
{
    const float* x = (const float*)d_in[0];
    const float *cw[4], *cbv[4], *bg[4], *bb[4], *bm[4], *bv[4];
    for (int i = 0; i < 4; ++i) {
        cw[i]  = (const float*)d_in[1 + 6 * i + 0];
        cbv[i] = (const float*)d_in[1 + 6 * i + 1];
        bg[i]  = (const float*)d_in[1 + 6 * i + 2];
        bb[i]  = (const float*)d_in[1 + 6 * i + 3];
        bm[i]  = (const float*)d_in[1 + 6 * i + 4];
        bv[i]  = (const float*)d_in[1 + 6 * i + 5];
    }
    const float* gw1 = (const float*)d_in[25];
    const float* gb1 = (const float*)d_in[26];
    const float* gw2 = (const float*)d_in[27];
    const float* gb2 = (const float*)d_in[28];
    const float* clw = (const float*)d_in[29];
    const float* clb = (const float*)d_in[30];

    char* wsb = (char*)d_ws;
    f16* a1h = (f16*)(wsb + 0);
    f16* a1l = (f16*)(wsb + 16777216);
    f16* a2h = (f16*)(wsb + 33554432);
    f16* a2l = (f16*)(wsb + 41943040);
    f16* W2h = (f16*)(wsb + 50331648);
    f16* W2l = (f16*)(wsb + 50368512);
    f16* W3h = (f16*)(wsb + 50405376);
    f16* W3l = (f16*)(wsb + 50552832);
    f16* W4h = (f16*)(wsb + 50700288);
    f16* W4l = (f16*)(wsb + 51290112);
    float* B2 = (float*)(wsb + 51879936);
    float* B3 = (float*)(wsb + 51880192);
    float* B4 = (float*)(wsb + 51880704);
    float* feats  = (float*)(wsb + 51881728);
    float* logits = (float*)(wsb + 52406016);
    float* conf   = (float*)(wsb + 85174016);
    float* rs     = (float*)(wsb + 85206784);
    unsigned char* Dcap = (unsigned char*)(wsb + 85239552);
    int*   sel  = (int*)(wsb + 85247744);
    float* selw = (float*)(wsb + 85251840);
    f16* a3h = a1h;
    f16* a3l = a1l;

    float* outF  = (float*)d_out;
    float* outRS = outF + 512 * 1000;
    float* outD  = outRS + 512 * 16;

    hipMemsetAsync(feats, 0, 512 * 256 * sizeof(float), stream);
    hipLaunchKernelGGL((prep_weights<32, 64>), dim3(9), dim3(256), 0, stream,
                       cw[1], cbv[1], bg[1], bb[1], bm[1], bv[1], W2h, W2l, B2);
    hipLaunchKernelGGL((prep_weights<64, 128>), dim3(36), dim3(256), 0, stream,
                       cw[2], cbv[2], bg[2], bb[2], bm[2], bv[2], W3h, W3l, B3);
    hipLaunchKernelGGL((prep_weights<128, 256>), dim3(144), dim3(256), 0, stream,
                       cw[3], cbv[3], bg[3], bb[3], bm[3], bv[3], W4h, W4l, B4);

    for (int c = 0; c < 8; ++c) {
        const float* xin = x + (size_t)c * 64 * 3 * 64 * 64;
        hipLaunchKernelGGL(conv1_kernel, dim3(2, 4, 64), dim3(256), 0, stream,
                           xin, cw[0], cbv[0], bg[0], bb[0], bm[0], bv[0], a1h, a1l);
        // conv2: NXB=1, NTILES=8 -> nwg=512
        hipLaunchKernelGGL((conv_mfma<32, 64, 64, 1, 8, true, false>),
                           dim3(512), dim3(512), 0, stream,
                           a1h, a1l, W2h, W2l, B2, a2h, a2l, (float*)nullptr);
        // conv3: NXB=2, NTILES=2 -> nwg=256
        hipLaunchKernelGGL((conv_mfma<64, 128, 32, 2, 2, false, false>),
                           dim3(256), dim3(512), 0, stream,
                           a2h, a2l, W3h, W3l, B3, a3h, a3l, (float*)nullptr);
        // conv4: NXB=4, NTILES=2 -> nwg=512
        hipLaunchKernelGGL((conv_mfma<128, 256, 32, 4, 2, true, true>),
                           dim3(512), dim3(512), 0, stream,
                           a3h, a3l, W4h, W4l, B4, (f16*)nullptr, (f16*)nullptr,
                           feats + (size_t)c * 64 * 256);
    }

    hipLaunchKernelGGL(gemm_logits, dim3(250, 8), dim3(256), 0, stream,
                       feats, clw, clb, logits);
    hipLaunchKernelGGL(softmax_ent, dim3(8192), dim3(256), 0, stream, logits, conf);
    hipLaunchKernelGGL(gate_kernel, dim3(512), dim3(128), 0, stream,
                       feats, gw1, gb1, gw2, gb2, conf, rs, outRS);
    hipLaunchKernelGGL(capacity_topk, dim3(16), dim3(512), 0, stream, rs, Dcap);
    hipLaunchKernelGGL(token_topk, dim3(2), dim3(256), 0, stream,
                       rs, Dcap, sel, selw, outD);
    hipLaunchKernelGGL(combine_kernel, dim3(4, 512), dim3(256), 0, stream,
                       logits, sel, selw, outF);
}